// Round 15
// baseline (237.582 us; speedup 1.0000x reference)
//
#include <hip/hip_runtime.h>
#include <hip/hip_bf16.h>

// Problem constants
#define BTOT 32768
#define NPOS 56            // 7*8
#define CNT1 1835008.0f    // BTOT*NPOS
#define LOG2E 1.4426950408889634f

// ws float offsets
#define WS_SUM1 0
#define WS_SSQ1 16
#define WS_SUM2 32
#define WS_SSQ2 64
#define WS_A1   96
#define WS_D1   112
#define WS_A2   128
#define WS_D2   160
#define WS_W2R  200        // f16 [32 c2][160]  (k = shift*16 + c1, shift 9 = zeros)
#define WS_VWH  2760       // f16 [32 c][32 cc]
#define WS_W1BF 3272       // f16 [256 n][1792 k'] with k' = pos*32 + c2
#define WS_WHD  232648     // f16 [256][256] (mu rows 0..127, lv rows 128..255)
#define WS_Y2H  265416     // f16 [32768][1792]: y2 pre-BN, later overwritten by h
// total = 29625544 floats ~= 118.5 MB

typedef __attribute__((ext_vector_type(4))) float f32x4;
typedef __attribute__((ext_vector_type(8))) _Float16 f16x8;

#define H1S 40             // h1 row stride (ushorts): 80 B, breaks 8-way bank conflict

static __device__ __forceinline__ ushort f2h(float f) {
  _Float16 h = (_Float16)f; return __builtin_bit_cast(ushort, h);
}
static __device__ __forceinline__ float h2f(ushort u) {
  _Float16 h = __builtin_bit_cast(_Float16, u); return (float)h;
}
static __device__ __forceinline__ uint pk2(float a, float b) {
  auto t = __builtin_amdgcn_cvt_pkrtz(a, b);
  return __builtin_bit_cast(uint, t);
}
static __device__ __forceinline__ uint pkfma(uint a, uint b, uint c) {
  uint d; asm("v_pk_fma_f16 %0, %1, %2, %3" : "=v"(d) : "v"(a), "v"(b), "v"(c)); return d;
}
static __device__ __forceinline__ uint pkmax0(uint a) {
  uint d; asm("v_pk_max_f16 %0, %1, %2" : "=v"(d) : "v"(a), "v"(0u)); return d;
}
// async global->LDS, 16B per lane; LDS dest is wave-uniform base + lane*16
static __device__ __forceinline__ void gload_lds16(const void* g, void* l) {
  __builtin_amdgcn_global_load_lds(
      (const __attribute__((address_space(1))) void*)g,
      (__attribute__((address_space(3))) void*)l, 16, 0, 0);
}

// ---------------- K0: conv1 batch stats (blocks 0..511) + weight pack (512..1535) ----------------
__global__ __launch_bounds__(256) void k_prep(const float* __restrict__ x,
    const float* __restrict__ w1, const float* __restrict__ w2,
    const float* __restrict__ vw, const float* __restrict__ fw,
    const float* __restrict__ muw, const float* __restrict__ lvw,
    float* __restrict__ ws) {
  int bid = blockIdx.x;
  if (bid >= 512) {
    // ------- pack path -------
    int t = (bid - 512) * 256 + threadIdx.x;
    int stride = 1024 * 256;
    ushort* w2r = (ushort*)(ws + WS_W2R);
    for (int d = t; d < 5120; d += stride) {
      int c2 = d / 160, rem = d % 160, s = rem >> 4, c1 = rem & 15;
      w2r[d] = f2h(s < 9 ? w2[c2 * 144 + c1 * 9 + s] : 0.f);
    }
    ushort* vwh = (ushort*)(ws + WS_VWH);
    for (int d = t; d < 1024; d += stride) vwh[d] = f2h(vw[d]);
    ushort* w1b = (ushort*)(ws + WS_W1BF);
    for (int d = t; d < 458752; d += stride) {
      int n = d / 1792, kk = d % 1792, pos = kk >> 5, c2 = kk & 31;
      w1b[d] = f2h(fw[n * 1792 + c2 * 56 + pos]);
    }
    ushort* whd = (ushort*)(ws + WS_WHD);
    for (int d = t; d < 65536; d += stride) {
      int n2 = d >> 8, kk = d & 255;
      whd[d] = f2h(n2 < 128 ? muw[n2 * 256 + kk] : lvw[(n2 - 128) * 256 + kk]);
    }
    return;
  }
  // ------- stats1 path (wave-private LDS: no barriers needed) -------
  __shared__ float xbs[4][96];
  int tid = threadIdx.x, wv = tid >> 6, lane = tid & 63;
  int c = lane >> 2, nsub = lane & 3;
  float wr[9];
#pragma unroll
  for (int k = 0; k < 9; ++k) wr[k] = w1[c * 9 + k];
  float s = 0.f, ss = 0.f;
  float* xsp = xbs[wv];
  for (int i = lane; i < 96; i += 64) xsp[i] = 0.f;
  for (int it = 0; it < 16; ++it) {
    int b = bid * 64 + wv * 16 + it;
    if (lane < 56) xsp[((lane >> 3) + 1) * 10 + (lane & 7) + 1] = x[(size_t)b * NPOS + lane];
#pragma unroll
    for (int i = 0; i < 14; ++i) {
      int n = nsub * 14 + i;
      int base = (n >> 3) * 10 + (n & 7);
      float acc = 0.f;
#pragma unroll
      for (int ky = 0; ky < 3; ++ky)
#pragma unroll
        for (int kx = 0; kx < 3; ++kx)
          acc += wr[ky * 3 + kx] * xsp[base + ky * 10 + kx];
      s += acc; ss += acc * acc;
    }
  }
  s += __shfl_xor(s, 1);  s += __shfl_xor(s, 2);
  ss += __shfl_xor(ss, 1); ss += __shfl_xor(ss, 2);
  if ((lane & 3) == 0) {
    atomicAdd(&ws[WS_SUM1 + c], s);
    atomicAdd(&ws[WS_SSQ1 + c], ss);
  }
}

// ---------------- finalize BN stats -> scale/shift ----------------
__global__ void k_finalize(const float* __restrict__ bnw, const float* __restrict__ bnb,
    float* __restrict__ ws, int nc, int so, int qo, int ao, int dof) {
  int c = threadIdx.x;
  if (c < nc) {
    float mean = ws[so + c] / CNT1;
    float var = ws[qo + c] / CNT1 - mean * mean;
    float a = bnw[c] * rsqrtf(var + 1e-5f);
    ws[ao + c] = a;
    ws[dof + c] = bnb[c] - a * mean;
  }
}

// ---------------- K2: conv1 + conv2(MFMA) -> y2 (f16, direct global) + bn2 stats ----------------
__global__ __launch_bounds__(256) void k_conv(const float* __restrict__ x,
    const float* __restrict__ w1, float* __restrict__ ws) {
  __shared__ ushort h1T[4][112 * H1S];  // per-wave [112 padded-pos][H1S stride, c1 in 0..15]
  __shared__ float xs4[4][96];
  __shared__ float sb[32], ssb[32];
  const ushort* w2r = (const ushort*)(ws + WS_W2R);
  ushort* y2h = (ushort*)(ws + WS_Y2H);
  int tid = threadIdx.x, wv = tid >> 6, lane = tid & 63;
  int lr = lane & 15, lk = lane >> 4;
  if (tid < 32) { sb[tid] = 0.f; ssb[tid] = 0.f; }
  ushort* h1 = h1T[wv];
  float* xsp = xs4[wv];
  for (int i = lane; i < 56 * H1S; i += 64) ((uint*)h1)[i] = 0;
  for (int i = lane; i < 96; i += 64) xsp[i] = 0.f;
  // A-fragments of conv2 weights (constant per kernel)
  f16x8 afr[2][5];
#pragma unroll
  for (int mi = 0; mi < 2; ++mi)
#pragma unroll
    for (int s2 = 0; s2 < 5; ++s2)
      afr[mi][s2] = *(const f16x8*)(w2r + (mi * 16 + lr) * 160 + s2 * 32 + lk * 8);
  // conv1 setup
  int c1l = lane >> 2, nsub = lane & 3;
  float wr[9];
#pragma unroll
  for (int k = 0; k < 9; ++k) wr[k] = w1[c1l * 9 + k];
  float a1 = ws[WS_A1 + c1l], d1 = ws[WS_D1 + c1l];
  // B-frag geometry
  int hi = lk >> 1, lo = lk & 1;
  int base4[4];
#pragma unroll
  for (int ni = 0; ni < 4; ++ni) {
    int n = lr + 16 * ni;
    base4[ni] = (n < 56) ? (n >> 3) * 10 + (n & 7) : 88;  // >=56 -> all-zero rows
  }
  const int dA_[5] = {0, 2, 11, 20, 22};
  const int dB_[5] = {1, 10, 12, 21, 0};
  float s8[8], ss8[8];
#pragma unroll
  for (int i = 0; i < 8; ++i) { s8[i] = 0.f; ss8[i] = 0.f; }
  __syncthreads();

  for (int r8 = 0; r8 < 8; ++r8) {
    int b = blockIdx.x * 32 + wv * 8 + r8;
    if (lane < 56) xsp[((lane >> 3) + 1) * 10 + (lane & 7) + 1] = x[(size_t)b * NPOS + lane];
    // conv1 + bn1 + relu -> h1T (wave-private, LDS ops in-order within wave)
#pragma unroll
    for (int i = 0; i < 14; ++i) {
      int n = nsub * 14 + i;
      int base = (n >> 3) * 10 + (n & 7);
      float acc = 0.f;
#pragma unroll
      for (int ky = 0; ky < 3; ++ky)
#pragma unroll
        for (int kx = 0; kx < 3; ++kx)
          acc += wr[ky * 3 + kx] * xsp[base + ky * 10 + kx];
      h1[(base + 11) * H1S + c1l] = f2h(fmaxf(acc * a1 + d1, 0.f));
    }
    // conv2 via MFMA: y2[c2][pos] = sum_k w2r[c2][k] * h1shift[k][pos]
    f32x4 acc2[2][4];
#pragma unroll
    for (int mi = 0; mi < 2; ++mi)
#pragma unroll
      for (int ni = 0; ni < 4; ++ni) { f32x4 z = {0.f, 0.f, 0.f, 0.f}; acc2[mi][ni] = z; }
#pragma unroll
    for (int s2 = 0; s2 < 5; ++s2) {
      f16x8 bf[4];
#pragma unroll
      for (int ni = 0; ni < 4; ++ni) {
        int row;
        if (s2 == 4) row = hi ? 104 : (base4[ni] + 22);
        else row = base4[ni] + (hi ? dB_[s2] : dA_[s2]);
        bf[ni] = *(const f16x8*)(h1 + row * H1S + lo * 8);
      }
#pragma unroll
      for (int mi = 0; mi < 2; ++mi)
#pragma unroll
        for (int ni = 0; ni < 4; ++ni)
          acc2[mi][ni] = __builtin_amdgcn_mfma_f32_16x16x32_f16(afr[mi][s2], bf[ni], acc2[mi][ni], 0, 0, 0);
    }
    // stats + direct global store [pos][c2] as uint2 (no LDS bounce)
    uint2* dst = (uint2*)(y2h + (size_t)b * 1792);
#pragma unroll
    for (int mi = 0; mi < 2; ++mi)
#pragma unroll
      for (int ni = 0; ni < 4; ++ni) {
        f32x4 v = acc2[mi][ni];
        int pos = lr + 16 * ni;
        s8[mi * 4 + 0] += v[0]; ss8[mi * 4 + 0] += v[0] * v[0];
        s8[mi * 4 + 1] += v[1]; ss8[mi * 4 + 1] += v[1] * v[1];
        s8[mi * 4 + 2] += v[2]; ss8[mi * 4 + 2] += v[2] * v[2];
        s8[mi * 4 + 3] += v[3]; ss8[mi * 4 + 3] += v[3] * v[3];
        if (pos < 56) {
          uint2 pp;
          pp.x = pk2(v[0], v[1]);
          pp.y = pk2(v[2], v[3]);
          dst[pos * 8 + mi * 4 + lk] = pp;
        }
      }
  }
  // reduce stats over the 16 pos-col lanes
#pragma unroll
  for (int i = 0; i < 8; ++i) {
    s8[i] += __shfl_xor(s8[i], 1);  s8[i] += __shfl_xor(s8[i], 2);
    s8[i] += __shfl_xor(s8[i], 4);  s8[i] += __shfl_xor(s8[i], 8);
    ss8[i] += __shfl_xor(ss8[i], 1); ss8[i] += __shfl_xor(ss8[i], 2);
    ss8[i] += __shfl_xor(ss8[i], 4); ss8[i] += __shfl_xor(ss8[i], 8);
  }
  if (lr == 0) {
#pragma unroll
    for (int i = 0; i < 8; ++i) {
      int c2 = lk * 4 + (i & 3) + 16 * (i >> 2);
      atomicAdd(&sb[c2], s8[i]);
      atomicAdd(&ssb[c2], ss8[i]);
    }
  }
  __syncthreads();
  if (tid < 32) {
    atomicAdd(&ws[WS_SUM2 + tid], sb[tid]);
    atomicAdd(&ws[WS_SSQ2 + tid], ssb[tid]);
  }
}

// ---------------- K3: attention; 2048 blocks x 16 samples; 2-sample pipelined ----------------
__global__ __launch_bounds__(256) void k_attn(
    const float* __restrict__ qw, const float* __restrict__ qb_,
    const float* __restrict__ kw, const float* __restrict__ kb_,
    const float* __restrict__ vb_, const float* __restrict__ gp,
    float* __restrict__ ws) {
  __shared__ ushort h2m[4][4096];   // per-wave 2 halves of [pos][c2] f16, XOR (row&3)<<4
  __shared__ ushort Pm[4][4096];    // [i][j] f16, XOR (row&7)<<4
  __shared__ ushort gm_[4][2048];   // [c][j] f16, XOR (row&7)<<4
  const ushort* vwh = (const ushort*)(ws + WS_VWH);
  ushort* y2h = (ushort*)(ws + WS_Y2H);
  int tid = threadIdx.x, wv = tid >> 6, lane = tid & 63;
  int lr = lane & 15, lk = lane >> 4;
  ushort* h2b = h2m[wv]; ushort* Pl = Pm[wv]; ushort* gl = gm_[wv];
  for (int i = lane; i < 2048; i += 64) ((uint*)h2b)[i] = 0;   // zero both halves (pad rows stay 0)
  float gamma = gp[0];
  // hoisted: v-weight B-frags
  f16x8 vwf[2];
#pragma unroll
  for (int ni = 0; ni < 2; ++ni)
    vwf[ni] = *(const f16x8*)(vwh + (lr + 16 * ni) * 32 + lk * 8);
  // hoisted: packed BN constants (f16x2 pairs over cc)
  uint a2pk[16], d2pk[16];
#pragma unroll
  for (int j = 0; j < 16; ++j) {
    a2pk[j] = pk2(ws[WS_A2 + 2 * j], ws[WS_A2 + 2 * j + 1]);
    d2pk[j] = pk2(ws[WS_D2 + 2 * j], ws[WS_D2 + 2 * j + 1]);
  }
  // hoisted: vb pairs for epilogue (c = cm*16 + lk*4 + r)
  uint vbpk[2][2];
#pragma unroll
  for (int cm = 0; cm < 2; ++cm) {
    int c0 = cm * 16 + lk * 4;
    vbpk[cm][0] = pk2(vb_[c0 + 0], vb_[c0 + 1]);
    vbpk[cm][1] = pk2(vb_[c0 + 2], vb_[c0 + 3]);
  }
  uint gammapk = pk2(gamma, gamma);
  // hoisted: qk projection A-frag: rows 0..3 = qw*log2e, 4..7 = kw, 8..15 = 0
  f16x8 qkwA;
  {
    float aw[8];
#pragma unroll
    for (int e = 0; e < 8; ++e) aw[e] = 0.f;
    if (lr < 4) {
#pragma unroll
      for (int e = 0; e < 8; ++e) aw[e] = qw[lr * 32 + lk * 8 + e] * LOG2E;
    } else if (lr < 8) {
#pragma unroll
      for (int e = 0; e < 8; ++e) aw[e] = kw[(lr - 4) * 32 + lk * 8 + e];
    }
    uint4 wq;
    wq.x = pk2(aw[0], aw[1]); wq.y = pk2(aw[2], aw[3]);
    wq.z = pk2(aw[4], aw[5]); wq.w = pk2(aw[6], aw[7]);
    qkwA = __builtin_bit_cast(f16x8, wq);
  }
  // hoisted: per-lane o-bias for projection output rows o = lk*4+r
  f32x4 biasv;
#pragma unroll
  for (int r = 0; r < 4; ++r) {
    int o = lk * 4 + r;
    biasv[r] = (o < 4) ? qb_[o] * LOG2E : ((o < 8) ? kb_[o - 4] : 0.f);
  }
  f32x4 zz = {0.f, 0.f, 0.f, 0.f};
  int b0 = blockIdx.x * 16 + wv * 4;

  // ---- prologue: load+BN sample 0 into h2 half 0; prefetch sample 1 ----
  uint4 pref[4];
  if (lane < 56) {
    const uint4* s0 = (const uint4*)y2h + (size_t)b0 * 224 + lane * 4;
#pragma unroll
    for (int g = 0; g < 4; ++g) pref[g] = s0[g];
#pragma unroll
    for (int g = 0; g < 4; ++g) {
      uint4 u = pref[g];
      uint4 hh;
      hh.x = pkmax0(pkfma(u.x, a2pk[g * 4 + 0], d2pk[g * 4 + 0]));
      hh.y = pkmax0(pkfma(u.y, a2pk[g * 4 + 1], d2pk[g * 4 + 1]));
      hh.z = pkmax0(pkfma(u.z, a2pk[g * 4 + 2], d2pk[g * 4 + 2]));
      hh.w = pkmax0(pkfma(u.w, a2pk[g * 4 + 3], d2pk[g * 4 + 3]));
      *(uint4*)((char*)h2b + ((lane * 64 + g * 16) ^ ((lane & 3) << 4))) = hh;
    }
    const uint4* s1 = (const uint4*)y2h + (size_t)(b0 + 1) * 224 + lane * 4;
#pragma unroll
    for (int g = 0; g < 4; ++g) pref[g] = s1[g];
  }
  int cur = 0;

  for (int r8 = 0; r8 < 4; ++r8) {
    int b = b0 + r8;
    ushort* h2 = h2b + cur * 2048;
    ushort* h2n = h2b + (cur ^ 1) * 2048;
    // ---- stage 1: QK^T = qkw @ h2^T via MFMA (4 tiles over pos) ----
    f32x4 vqk[4];
#pragma unroll
    for (int ni = 0; ni < 4; ++ni) {
      int pos = ni * 16 + lr;
      f16x8 hb2 = *(const f16x8*)((const char*)h2 + ((pos * 64 + lk * 16) ^ ((pos & 3) << 4)));
      f32x4 a = __builtin_amdgcn_mfma_f32_16x16x32_f16(qkwA, hb2, zz, 0, 0, 0);
      a[0] += biasv[0]; a[1] += biasv[1]; a[2] += biasv[2]; a[3] += biasv[3];
      vqk[ni] = a;
    }
    // ---- build score-MFMA fragments via shuffles ----
    f16x8 qfr[4], kfr[4];
#pragma unroll
    for (int t = 0; t < 4; ++t) {
      float q0 = __shfl(vqk[t][0], lr),      q1 = __shfl(vqk[t][1], lr);
      float q2 = __shfl(vqk[t][2], lr),      q3 = __shfl(vqk[t][3], lr);
      float k0 = __shfl(vqk[t][0], 16 + lr), k1 = __shfl(vqk[t][1], 16 + lr);
      float k2 = __shfl(vqk[t][2], 16 + lr), k3 = __shfl(vqk[t][3], 16 + lr);
      uint4 uq = {0u, 0u, 0u, 0u}, uk = {0u, 0u, 0u, 0u};
      if (lk == 0) {
        uq.x = pk2(q0, q1); uq.y = pk2(q2, q3);
        uk.x = pk2(k0, k1); uk.y = pk2(k2, k3);
      }
      qfr[t] = __builtin_bit_cast(f16x8, uq);
      kfr[t] = __builtin_bit_cast(f16x8, uk);
    }
    // ---- scores: S^T[j][i] via 16 MFMAs ----
    f32x4 sac[4][4];
#pragma unroll
    for (int mi = 0; mi < 4; ++mi)
#pragma unroll
      for (int ni = 0; ni < 4; ++ni)
        sac[mi][ni] = __builtin_amdgcn_mfma_f32_16x16x32_f16(kfr[mi], qfr[ni], zz, 0, 0, 0);
    // ---- softmax per i-row, clamp-no-max, masked j>=56; inv kept in registers ----
    float invv4[4];
#pragma unroll
    for (int ni = 0; ni < 4; ++ni) {
      float den = 0.f;
      float ev[4][4];
#pragma unroll
      for (int mi = 0; mi < 4; ++mi)
#pragma unroll
        for (int r = 0; r < 4; ++r) {
          float e = __builtin_amdgcn_exp2f(fminf(sac[mi][ni][r], 15.f));
          if (mi == 3) e = (lk < 2) ? e : 0.f;
          ev[mi][r] = e;
          den += e;
        }
      den += __shfl_xor(den, 16);
      den += __shfl_xor(den, 32);
      invv4[ni] = 1.f / den;
      int i = ni * 16 + lr;
#pragma unroll
      for (int mi = 0; mi < 4; ++mi) {
        uint2 pp;
        pp.x = pk2(ev[mi][0], ev[mi][1]);
        pp.y = pk2(ev[mi][2], ev[mi][3]);
        *(uint2*)((char*)Pl + ((i * 128 + mi * 32 + lk * 8) ^ ((lr & 7) << 4))) = pp;
      }
    }
    // ---- pipeline: BN+store NEXT sample into other h2 half (overlaps with PV below) ----
    if (r8 < 3 && lane < 56) {
#pragma unroll
      for (int g = 0; g < 4; ++g) {
        uint4 u = pref[g];
        uint4 hh;
        hh.x = pkmax0(pkfma(u.x, a2pk[g * 4 + 0], d2pk[g * 4 + 0]));
        hh.y = pkmax0(pkfma(u.y, a2pk[g * 4 + 1], d2pk[g * 4 + 1]));
        hh.z = pkmax0(pkfma(u.z, a2pk[g * 4 + 2], d2pk[g * 4 + 2]));
        hh.w = pkmax0(pkfma(u.w, a2pk[g * 4 + 3], d2pk[g * 4 + 3]));
        *(uint4*)((char*)h2n + ((lane * 64 + g * 16) ^ ((lane & 3) << 4))) = hh;
      }
      if (r8 < 2) {
        const uint4* sn = (const uint4*)y2h + (size_t)(b + 2) * 224 + lane * 4;
#pragma unroll
        for (int g = 0; g < 4; ++g) pref[g] = sn[g];
      }
    }
    // ---- gT = h2 @ vw^T : [64 j][32 c] ----
    f32x4 ga[4][2];
#pragma unroll
    for (int mi = 0; mi < 4; ++mi) {
      int rw = lr + 16 * mi;
      f16x8 af = *(const f16x8*)((const char*)h2 + ((rw * 64 + lk * 16) ^ ((rw & 3) << 4)));
#pragma unroll
      for (int ni = 0; ni < 2; ++ni)
        ga[mi][ni] = __builtin_amdgcn_mfma_f32_16x16x32_f16(af, vwf[ni], zz, 0, 0, 0);
    }
#pragma unroll
    for (int mi = 0; mi < 4; ++mi)
#pragma unroll
      for (int ni = 0; ni < 2; ++ni) {
        f32x4 v = ga[mi][ni];
        int c = lr + 16 * ni;
        int jb2 = (lk * 4 + 16 * mi) * 2;
        uint2 pp;
        pp.x = pk2(v[0], v[1]);
        pp.y = pk2(v[2], v[3]);
        *(uint2*)((char*)gl + ((c * 128 + jb2) ^ ((c & 7) << 4))) = pp;
      }
    // ---- swapped PV: out^T[c][i] = g @ P^T ----
    f32x4 oa2[2][4];
#pragma unroll
    for (int cm = 0; cm < 2; ++cm)
#pragma unroll
      for (int ni = 0; ni < 4; ++ni) oa2[cm][ni] = zz;
#pragma unroll
    for (int ks = 0; ks < 2; ++ks) {
      f16x8 gaf[2];
#pragma unroll
      for (int cm = 0; cm < 2; ++cm) {
        int c = lr + 16 * cm;
        gaf[cm] = *(const f16x8*)((const char*)gl + ((c * 128 + ks * 64 + lk * 16) ^ ((c & 7) << 4)));
      }
      f16x8 pbf[4];
#pragma unroll
      for (int ni = 0; ni < 4; ++ni) {
        int i = lr + 16 * ni;
        pbf[ni] = *(const f16x8*)((const char*)Pl + ((i * 128 + ks * 64 + lk * 16) ^ ((i & 7) << 4)));
      }
#pragma unroll
      for (int cm = 0; cm < 2; ++cm)
#pragma unroll
        for (int ni = 0; ni < 4; ++ni)
          oa2[cm][ni] = __builtin_amdgcn_mfma_f32_16x16x32_f16(gaf[cm], pbf[ni], oa2[cm][ni], 0, 0, 0);
    }
    // ---- epilogue: h = gamma*(vb + inv*out) + h2 -> DIRECT global store ----
    uint invpk[4];
#pragma unroll
    for (int ni = 0; ni < 4; ++ni) invpk[ni] = pk2(invv4[ni], invv4[ni]);
#pragma unroll
    for (int cm = 0; cm < 2; ++cm)
#pragma unroll
      for (int ni = 0; ni < 4; ++ni) {
        int i = lr + 16 * ni;
        uint2 h2v = *(const uint2*)((const char*)h2 + ((i * 64 + cm * 32 + lk * 8) ^ ((i & 3) << 4)));
        uint o01 = pk2(oa2[cm][ni][0], oa2[cm][ni][1]);
        uint o23 = pk2(oa2[cm][ni][2], oa2[cm][ni][3]);
        uint t0 = pkfma(o01, invpk[ni], vbpk[cm][0]);
        uint t1 = pkfma(o23, invpk[ni], vbpk[cm][1]);
        uint2 rr2;
        rr2.x = pkfma(t0, gammapk, h2v.x);
        rr2.y = pkfma(t1, gammapk, h2v.y);
        if (i < 56)
          *(uint2*)(y2h + (size_t)b * 1792 + i * 32 + cm * 16 + lk * 4) = rr2;
      }
    cur ^= 1;
  }
}

// ---------------- K4: fc1 + heads via f16 MFMA, async global->LDS staging ----------------
__global__ __launch_bounds__(256) void k_fc(
    const float* __restrict__ fc1b, const float* __restrict__ mub,
    const float* __restrict__ lvb, const float* __restrict__ ws,
    float* __restrict__ out) {
  __shared__ __align__(16) ushort At[64 * 64];
  __shared__ __align__(16) ushort Bt[256 * 64];
  __shared__ __align__(16) ushort Ft[64 * 256];
  const ushort* hbuf = (const ushort*)(ws + WS_Y2H);
  const ushort* w1bf = (const ushort*)(ws + WS_W1BF);
  const ushort* whd  = (const ushort*)(ws + WS_WHD);
  int tid = threadIdx.x, wv = tid >> 6, lane = tid & 63;
  int m0 = blockIdx.x * 64;
  int lr = lane & 15, lk = lane >> 4;
  int lrow8 = lane >> 3;                 // sub-row within a 1KB lds-load call
  int lchunk = (lane & 7) ^ lrow8;       // pre-swizzled source chunk (matches XOR read layout)

  f32x4 acc[4][4];
#pragma unroll
  for (int mi = 0; mi < 4; ++mi)
#pragma unroll
    for (int ni = 0; ni < 4; ++ni) { f32x4 z = {0.f, 0.f, 0.f, 0.f}; acc[mi][ni] = z; }

  for (int kk = 0; kk < 1792; kk += 64) {
    // stage A [64][64] via async global->LDS: 2 calls/wave, 8 rows each
#pragma unroll
    for (int j = 0; j < 2; ++j) {
      int r = wv * 16 + j * 8 + lrow8;
      gload_lds16(&hbuf[(size_t)(m0 + r) * 1792 + kk + lchunk * 8],
                  &At[(wv * 16 + j * 8) * 64]);
    }
    // stage B [256][64]: 8 calls/wave
#pragma unroll
    for (int j = 0; j < 8; ++j) {
      int r = wv * 64 + j * 8 + lrow8;
      gload_lds16(&w1bf[(size_t)r * 1792 + kk + lchunk * 8],
                  &Bt[(wv * 64 + j * 8) * 64]);
    }
    __syncthreads();
#pragma unroll
    for (int t2 = 0; t2 < 2; ++t2) {
      f16x8 af[4], bfr[4];
#pragma unroll
      for (int mi = 0; mi < 4; ++mi) {
        int rr = mi * 16 + lr;
        int ch = (t2 * 4 + lk) ^ (rr & 7);
        af[mi] = *(const f16x8*)&At[rr * 64 + ch * 8];
      }
#pragma unroll
      for (int ni = 0; ni < 4; ++ni) {
        int rr = wv * 64 + ni * 16 + lr;
        int ch = (t2 * 4 + lk) ^ (rr & 7);
        bfr[ni] = *(const f16x8*)&Bt[rr * 64 + ch * 8];
      }
#pragma unroll
      for (int mi = 0; mi < 4; ++mi)
#pragma unroll
        for (int ni = 0; ni < 4; ++ni)
          acc[mi][ni] = __builtin_amdgcn_mfma_f32_16x16x32_f16(af[mi], bfr[ni], acc[mi][ni], 0, 0, 0);
    }
    __syncthreads();
  }
#pragma unroll
  for (int ni = 0; ni < 4; ++ni) {
    int n = wv * 64 + ni * 16 + lr;
    float bj = fc1b[n];
    int lc = n >> 3;
    int nl = n & 7;
#pragma unroll
    for (int mi = 0; mi < 4; ++mi) {
      f32x4 v = acc[mi][ni];
#pragma unroll
      for (int r = 0; r < 4; ++r) {
        int m = mi * 16 + lk * 4 + r;
        int chs = (lc & ~7) | ((lc & 7) ^ (m & 7));
        Ft[m * 256 + chs * 8 + nl] = f2h(fmaxf(v[r] + bj, 0.f));
      }
    }
  }
  __syncthreads();
  f32x4 acc2[4][4];
#pragma unroll
  for (int mi = 0; mi < 4; ++mi)
#pragma unroll
    for (int ni = 0; ni < 4; ++ni) { f32x4 z = {0.f, 0.f, 0.f, 0.f}; acc2[mi][ni] = z; }
  for (int kk2 = 0; kk2 < 256; kk2 += 64) {
    // stage whd tile via async global->LDS (same swizzle mapping, stride 256)
#pragma unroll
    for (int j = 0; j < 8; ++j) {
      int r = wv * 64 + j * 8 + lrow8;
      gload_lds16(&whd[(size_t)r * 256 + kk2 + lchunk * 8],
                  &Bt[(wv * 64 + j * 8) * 64]);
    }
    __syncthreads();
#pragma unroll
    for (int t2 = 0; t2 < 2; ++t2) {
      f16x8 af[4], bfr[4];
#pragma unroll
      for (int mi = 0; mi < 4; ++mi) {
        int m = mi * 16 + lr;
        int lc = (kk2 >> 3) + t2 * 4 + lk;
        int chs = (lc & ~7) | ((lc & 7) ^ (m & 7));
        af[mi] = *(const f16x8*)&Ft[m * 256 + chs * 8];
      }
#pragma unroll
      for (int ni = 0; ni < 4; ++ni) {
        int rr = wv * 64 + ni * 16 + lr;
        int ch = (t2 * 4 + lk) ^ (rr & 7);
        bfr[ni] = *(const f16x8*)&Bt[rr * 64 + ch * 8];
      }
#pragma unroll
      for (int mi = 0; mi < 4; ++mi)
#pragma unroll
        for (int ni = 0; ni < 4; ++ni)
          acc2[mi][ni] = __builtin_amdgcn_mfma_f32_16x16x32_f16(af[mi], bfr[ni], acc2[mi][ni], 0, 0, 0);
    }
    __syncthreads();
  }
#pragma unroll
  for (int ni = 0; ni < 4; ++ni) {
    int n2 = wv * 64 + ni * 16 + lr;
    int isLv = (n2 >= 128);
    float bias2 = isLv ? lvb[n2 - 128] : mub[n2];
    size_t obase = isLv ? ((size_t)BTOT * 128 + (n2 - 128)) : (size_t)n2;
#pragma unroll
    for (int mi = 0; mi < 4; ++mi) {
      f32x4 v = acc2[mi][ni];
#pragma unroll
      for (int r = 0; r < 4; ++r) {
        int m = m0 + mi * 16 + lk * 4 + r;
        out[obase + (size_t)m * 128] = v[r] + bias2;
      }
    }
  }
}

extern "C" void kernel_launch(void* const* d_in, const int* in_sizes, int n_in,
                              void* d_out, int out_size, void* d_ws, size_t ws_size,
                              hipStream_t stream) {
  const float* x    = (const float*)d_in[0];
  const float* c1w  = (const float*)d_in[1];
  const float* bn1w = (const float*)d_in[3];
  const float* bn1b = (const float*)d_in[4];
  const float* c2w  = (const float*)d_in[5];
  const float* bn2w = (const float*)d_in[7];
  const float* bn2b = (const float*)d_in[8];
  const float* qw   = (const float*)d_in[9];
  const float* qb   = (const float*)d_in[10];
  const float* kw   = (const float*)d_in[11];
  const float* kb   = (const float*)d_in[12];
  const float* vw   = (const float*)d_in[13];
  const float* vb   = (const float*)d_in[14];
  const float* gm   = (const float*)d_in[15];
  const float* fw   = (const float*)d_in[16];
  const float* fb   = (const float*)d_in[17];
  const float* muw  = (const float*)d_in[18];
  const float* mub  = (const float*)d_in[19];
  const float* lvw  = (const float*)d_in[20];
  const float* lvb  = (const float*)d_in[21];
  float* ws = (float*)d_ws;
  float* out = (float*)d_out;

  hipMemsetAsync(d_ws, 0, 200 * sizeof(float), stream);
  hipLaunchKernelGGL(k_prep, dim3(1536), dim3(256), 0, stream,
                     x, c1w, c2w, vw, fw, muw, lvw, ws);
  hipLaunchKernelGGL(k_finalize, dim3(1), dim3(64), 0, stream, bn1w, bn1b, ws,
                     16, WS_SUM1, WS_SSQ1, WS_A1, WS_D1);
  hipLaunchKernelGGL(k_conv, dim3(1024), dim3(256), 0, stream, x, c1w, ws);
  hipLaunchKernelGGL(k_finalize, dim3(1), dim3(64), 0, stream, bn2w, bn2b, ws,
                     32, WS_SUM2, WS_SSQ2, WS_A2, WS_D2);
  hipLaunchKernelGGL(k_attn, dim3(2048), dim3(256), 0, stream,
                     qw, qb, kw, kb, vb, gm, ws);
  hipLaunchKernelGGL(k_fc, dim3(512), dim3(256), 0, stream, fb, mub, lvb, ws, out);
}

// Round 16
// 233.868 us; speedup vs baseline: 1.0159x; 1.0159x over previous
//
#include <hip/hip_runtime.h>
#include <hip/hip_bf16.h>

// Problem constants
#define BTOT 32768
#define NPOS 56            // 7*8
#define CNT1 1835008.0f    // BTOT*NPOS
#define LOG2E 1.4426950408889634f

// ws float offsets
#define WS_SUM1 0
#define WS_SSQ1 16
#define WS_SUM2 32
#define WS_SSQ2 64
#define WS_A1   96
#define WS_D1   112
#define WS_A2   128
#define WS_D2   160
#define WS_W2R  200        // f16 [32 c2][160]  (k = shift*16 + c1, shift 9 = zeros)
#define WS_VWH  2760       // f16 [32 c][32 cc]
#define WS_W1BF 3272       // f16 [256 n][1792 k'] with k' = pos*32 + c2
#define WS_WHD  232648     // f16 [256][256] (mu rows 0..127, lv rows 128..255)
#define WS_Y2H  265416     // f16 [32768][1792]: y2 pre-BN, later overwritten by h
// total = 29625544 floats ~= 118.5 MB

typedef __attribute__((ext_vector_type(4))) float f32x4;
typedef __attribute__((ext_vector_type(8))) _Float16 f16x8;

#define H1S 40             // h1 row stride (ushorts): 80 B, breaks 8-way bank conflict

static __device__ __forceinline__ ushort f2h(float f) {
  _Float16 h = (_Float16)f; return __builtin_bit_cast(ushort, h);
}
static __device__ __forceinline__ float h2f(ushort u) {
  _Float16 h = __builtin_bit_cast(_Float16, u); return (float)h;
}
static __device__ __forceinline__ uint pk2(float a, float b) {
  auto t = __builtin_amdgcn_cvt_pkrtz(a, b);
  return __builtin_bit_cast(uint, t);
}
static __device__ __forceinline__ uint pkfma(uint a, uint b, uint c) {
  uint d; asm("v_pk_fma_f16 %0, %1, %2, %3" : "=v"(d) : "v"(a), "v"(b), "v"(c)); return d;
}
static __device__ __forceinline__ uint pkmax0(uint a) {
  uint d; asm("v_pk_max_f16 %0, %1, %2" : "=v"(d) : "v"(a), "v"(0u)); return d;
}
// async global->LDS, 16B per lane; LDS dest is wave-uniform base + lane*16
static __device__ __forceinline__ void gload_lds16(const void* g, void* l) {
  __builtin_amdgcn_global_load_lds(
      (const __attribute__((address_space(1))) void*)g,
      (__attribute__((address_space(3))) void*)l, 16, 0, 0);
}

// ---------------- K0: conv1 batch stats (blocks 0..511) + weight pack (512..1535) ----------------
__global__ __launch_bounds__(256) void k_prep(const float* __restrict__ x,
    const float* __restrict__ w1, const float* __restrict__ w2,
    const float* __restrict__ vw, const float* __restrict__ fw,
    const float* __restrict__ muw, const float* __restrict__ lvw,
    float* __restrict__ ws) {
  int bid = blockIdx.x;
  if (bid >= 512) {
    // ------- pack path -------
    int t = (bid - 512) * 256 + threadIdx.x;
    int stride = 1024 * 256;
    ushort* w2r = (ushort*)(ws + WS_W2R);
    for (int d = t; d < 5120; d += stride) {
      int c2 = d / 160, rem = d % 160, s = rem >> 4, c1 = rem & 15;
      w2r[d] = f2h(s < 9 ? w2[c2 * 144 + c1 * 9 + s] : 0.f);
    }
    ushort* vwh = (ushort*)(ws + WS_VWH);
    for (int d = t; d < 1024; d += stride) vwh[d] = f2h(vw[d]);
    ushort* w1b = (ushort*)(ws + WS_W1BF);
    for (int d = t; d < 458752; d += stride) {
      int n = d / 1792, kk = d % 1792, pos = kk >> 5, c2 = kk & 31;
      w1b[d] = f2h(fw[n * 1792 + c2 * 56 + pos]);
    }
    ushort* whd = (ushort*)(ws + WS_WHD);
    for (int d = t; d < 65536; d += stride) {
      int n2 = d >> 8, kk = d & 255;
      whd[d] = f2h(n2 < 128 ? muw[n2 * 256 + kk] : lvw[(n2 - 128) * 256 + kk]);
    }
    return;
  }
  // ------- stats1 path (wave-private LDS: no barriers needed) -------
  __shared__ float xbs[4][96];
  int tid = threadIdx.x, wv = tid >> 6, lane = tid & 63;
  int c = lane >> 2, nsub = lane & 3;
  float wr[9];
#pragma unroll
  for (int k = 0; k < 9; ++k) wr[k] = w1[c * 9 + k];
  float s = 0.f, ss = 0.f;
  float* xsp = xbs[wv];
  for (int i = lane; i < 96; i += 64) xsp[i] = 0.f;
  for (int it = 0; it < 16; ++it) {
    int b = bid * 64 + wv * 16 + it;
    if (lane < 56) xsp[((lane >> 3) + 1) * 10 + (lane & 7) + 1] = x[(size_t)b * NPOS + lane];
#pragma unroll
    for (int i = 0; i < 14; ++i) {
      int n = nsub * 14 + i;
      int base = (n >> 3) * 10 + (n & 7);
      float acc = 0.f;
#pragma unroll
      for (int ky = 0; ky < 3; ++ky)
#pragma unroll
        for (int kx = 0; kx < 3; ++kx)
          acc += wr[ky * 3 + kx] * xsp[base + ky * 10 + kx];
      s += acc; ss += acc * acc;
    }
  }
  s += __shfl_xor(s, 1);  s += __shfl_xor(s, 2);
  ss += __shfl_xor(ss, 1); ss += __shfl_xor(ss, 2);
  if ((lane & 3) == 0) {
    atomicAdd(&ws[WS_SUM1 + c], s);
    atomicAdd(&ws[WS_SSQ1 + c], ss);
  }
}

// ---------------- finalize BN stats -> scale/shift ----------------
__global__ void k_finalize(const float* __restrict__ bnw, const float* __restrict__ bnb,
    float* __restrict__ ws, int nc, int so, int qo, int ao, int dof) {
  int c = threadIdx.x;
  if (c < nc) {
    float mean = ws[so + c] / CNT1;
    float var = ws[qo + c] / CNT1 - mean * mean;
    float a = bnw[c] * rsqrtf(var + 1e-5f);
    ws[ao + c] = a;
    ws[dof + c] = bnb[c] - a * mean;
  }
}

// ---------------- K2: conv1 + conv2(MFMA) -> y2 (f16, direct global) + bn2 stats ----------------
__global__ __launch_bounds__(256) void k_conv(const float* __restrict__ x,
    const float* __restrict__ w1, float* __restrict__ ws) {
  __shared__ ushort h1T[4][112 * H1S];  // per-wave [112 padded-pos][H1S stride, c1 in 0..15]
  __shared__ float xs4[4][96];
  __shared__ float sb[32], ssb[32];
  const ushort* w2r = (const ushort*)(ws + WS_W2R);
  ushort* y2h = (ushort*)(ws + WS_Y2H);
  int tid = threadIdx.x, wv = tid >> 6, lane = tid & 63;
  int lr = lane & 15, lk = lane >> 4;
  if (tid < 32) { sb[tid] = 0.f; ssb[tid] = 0.f; }
  ushort* h1 = h1T[wv];
  float* xsp = xs4[wv];
  for (int i = lane; i < 56 * H1S; i += 64) ((uint*)h1)[i] = 0;
  for (int i = lane; i < 96; i += 64) xsp[i] = 0.f;
  // A-fragments of conv2 weights (constant per kernel)
  f16x8 afr[2][5];
#pragma unroll
  for (int mi = 0; mi < 2; ++mi)
#pragma unroll
    for (int s2 = 0; s2 < 5; ++s2)
      afr[mi][s2] = *(const f16x8*)(w2r + (mi * 16 + lr) * 160 + s2 * 32 + lk * 8);
  // conv1 setup
  int c1l = lane >> 2, nsub = lane & 3;
  float wr[9];
#pragma unroll
  for (int k = 0; k < 9; ++k) wr[k] = w1[c1l * 9 + k];
  float a1 = ws[WS_A1 + c1l], d1 = ws[WS_D1 + c1l];
  // B-frag geometry
  int hi = lk >> 1, lo = lk & 1;
  int base4[4];
#pragma unroll
  for (int ni = 0; ni < 4; ++ni) {
    int n = lr + 16 * ni;
    base4[ni] = (n < 56) ? (n >> 3) * 10 + (n & 7) : 88;  // >=56 -> all-zero rows
  }
  const int dA_[5] = {0, 2, 11, 20, 22};
  const int dB_[5] = {1, 10, 12, 21, 0};
  float s8[8], ss8[8];
#pragma unroll
  for (int i = 0; i < 8; ++i) { s8[i] = 0.f; ss8[i] = 0.f; }
  __syncthreads();

  for (int r8 = 0; r8 < 8; ++r8) {
    int b = blockIdx.x * 32 + wv * 8 + r8;
    if (lane < 56) xsp[((lane >> 3) + 1) * 10 + (lane & 7) + 1] = x[(size_t)b * NPOS + lane];
    // conv1 + bn1 + relu -> h1T (wave-private, LDS ops in-order within wave)
#pragma unroll
    for (int i = 0; i < 14; ++i) {
      int n = nsub * 14 + i;
      int base = (n >> 3) * 10 + (n & 7);
      float acc = 0.f;
#pragma unroll
      for (int ky = 0; ky < 3; ++ky)
#pragma unroll
        for (int kx = 0; kx < 3; ++kx)
          acc += wr[ky * 3 + kx] * xsp[base + ky * 10 + kx];
      h1[(base + 11) * H1S + c1l] = f2h(fmaxf(acc * a1 + d1, 0.f));
    }
    // conv2 via MFMA: y2[c2][pos] = sum_k w2r[c2][k] * h1shift[k][pos]
    f32x4 acc2[2][4];
#pragma unroll
    for (int mi = 0; mi < 2; ++mi)
#pragma unroll
      for (int ni = 0; ni < 4; ++ni) { f32x4 z = {0.f, 0.f, 0.f, 0.f}; acc2[mi][ni] = z; }
#pragma unroll
    for (int s2 = 0; s2 < 5; ++s2) {
      f16x8 bf[4];
#pragma unroll
      for (int ni = 0; ni < 4; ++ni) {
        int row;
        if (s2 == 4) row = hi ? 104 : (base4[ni] + 22);
        else row = base4[ni] + (hi ? dB_[s2] : dA_[s2]);
        bf[ni] = *(const f16x8*)(h1 + row * H1S + lo * 8);
      }
#pragma unroll
      for (int mi = 0; mi < 2; ++mi)
#pragma unroll
        for (int ni = 0; ni < 4; ++ni)
          acc2[mi][ni] = __builtin_amdgcn_mfma_f32_16x16x32_f16(afr[mi][s2], bf[ni], acc2[mi][ni], 0, 0, 0);
    }
    // stats + direct global store [pos][c2] as uint2 (no LDS bounce)
    uint2* dst = (uint2*)(y2h + (size_t)b * 1792);
#pragma unroll
    for (int mi = 0; mi < 2; ++mi)
#pragma unroll
      for (int ni = 0; ni < 4; ++ni) {
        f32x4 v = acc2[mi][ni];
        int pos = lr + 16 * ni;
        s8[mi * 4 + 0] += v[0]; ss8[mi * 4 + 0] += v[0] * v[0];
        s8[mi * 4 + 1] += v[1]; ss8[mi * 4 + 1] += v[1] * v[1];
        s8[mi * 4 + 2] += v[2]; ss8[mi * 4 + 2] += v[2] * v[2];
        s8[mi * 4 + 3] += v[3]; ss8[mi * 4 + 3] += v[3] * v[3];
        if (pos < 56) {
          uint2 pp;
          pp.x = pk2(v[0], v[1]);
          pp.y = pk2(v[2], v[3]);
          dst[pos * 8 + mi * 4 + lk] = pp;
        }
      }
  }
  // reduce stats over the 16 pos-col lanes
#pragma unroll
  for (int i = 0; i < 8; ++i) {
    s8[i] += __shfl_xor(s8[i], 1);  s8[i] += __shfl_xor(s8[i], 2);
    s8[i] += __shfl_xor(s8[i], 4);  s8[i] += __shfl_xor(s8[i], 8);
    ss8[i] += __shfl_xor(ss8[i], 1); ss8[i] += __shfl_xor(ss8[i], 2);
    ss8[i] += __shfl_xor(ss8[i], 4); ss8[i] += __shfl_xor(ss8[i], 8);
  }
  if (lr == 0) {
#pragma unroll
    for (int i = 0; i < 8; ++i) {
      int c2 = lk * 4 + (i & 3) + 16 * (i >> 2);
      atomicAdd(&sb[c2], s8[i]);
      atomicAdd(&ssb[c2], ss8[i]);
    }
  }
  __syncthreads();
  if (tid < 32) {
    atomicAdd(&ws[WS_SUM2 + tid], sb[tid]);
    atomicAdd(&ws[WS_SSQ2 + tid], ssb[tid]);
  }
}

// ---------------- K3: attention; 2-sample pipelined; h2 double-buffered; setprio on MFMA ----------------
__global__ __launch_bounds__(256) void k_attn(
    const float* __restrict__ qw, const float* __restrict__ qb_,
    const float* __restrict__ kw, const float* __restrict__ kb_,
    const float* __restrict__ vb_, const float* __restrict__ gp,
    float* __restrict__ ws) {
  __shared__ ushort h2m[4][4096];   // per-wave 2 halves of [pos][c2] f16, XOR (row&3)<<4
  __shared__ ushort Pm[4][4096];    // [i][j] f16, XOR (row&7)<<4
  __shared__ ushort gm_[4][2048];   // [c][j] f16, XOR (row&7)<<4
  const ushort* vwh = (const ushort*)(ws + WS_VWH);
  ushort* y2h = (ushort*)(ws + WS_Y2H);
  int tid = threadIdx.x, wv = tid >> 6, lane = tid & 63;
  int lr = lane & 15, lk = lane >> 4;
  ushort* h2b = h2m[wv]; ushort* Pl = Pm[wv]; ushort* gl = gm_[wv];
  for (int i = lane; i < 2048; i += 64) ((uint*)h2b)[i] = 0;   // zero both halves (pad rows stay 0)
  float gamma = gp[0];
  // hoisted: v-weight B-frags
  f16x8 vwf[2];
#pragma unroll
  for (int ni = 0; ni < 2; ++ni)
    vwf[ni] = *(const f16x8*)(vwh + (lr + 16 * ni) * 32 + lk * 8);
  // hoisted: packed BN constants (f16x2 pairs over cc)
  uint a2pk[16], d2pk[16];
#pragma unroll
  for (int j = 0; j < 16; ++j) {
    a2pk[j] = pk2(ws[WS_A2 + 2 * j], ws[WS_A2 + 2 * j + 1]);
    d2pk[j] = pk2(ws[WS_D2 + 2 * j], ws[WS_D2 + 2 * j + 1]);
  }
  // hoisted: vb pairs for epilogue (c = cm*16 + lk*4 + r)
  uint vbpk[2][2];
#pragma unroll
  for (int cm = 0; cm < 2; ++cm) {
    int c0 = cm * 16 + lk * 4;
    vbpk[cm][0] = pk2(vb_[c0 + 0], vb_[c0 + 1]);
    vbpk[cm][1] = pk2(vb_[c0 + 2], vb_[c0 + 3]);
  }
  uint gammapk = pk2(gamma, gamma);
  // hoisted: qk projection A-frag: rows 0..3 = qw*log2e, 4..7 = kw, 8..15 = 0
  f16x8 qkwA;
  {
    float aw[8];
#pragma unroll
    for (int e = 0; e < 8; ++e) aw[e] = 0.f;
    if (lr < 4) {
#pragma unroll
      for (int e = 0; e < 8; ++e) aw[e] = qw[lr * 32 + lk * 8 + e] * LOG2E;
    } else if (lr < 8) {
#pragma unroll
      for (int e = 0; e < 8; ++e) aw[e] = kw[(lr - 4) * 32 + lk * 8 + e];
    }
    uint4 wq;
    wq.x = pk2(aw[0], aw[1]); wq.y = pk2(aw[2], aw[3]);
    wq.z = pk2(aw[4], aw[5]); wq.w = pk2(aw[6], aw[7]);
    qkwA = __builtin_bit_cast(f16x8, wq);
  }
  // hoisted: per-lane o-bias for projection output rows o = lk*4+r
  f32x4 biasv;
#pragma unroll
  for (int r = 0; r < 4; ++r) {
    int o = lk * 4 + r;
    biasv[r] = (o < 4) ? qb_[o] * LOG2E : ((o < 8) ? kb_[o - 4] : 0.f);
  }
  f32x4 zz = {0.f, 0.f, 0.f, 0.f};
  int b0 = blockIdx.x * 32 + wv * 8;

  // ---- prologue: load+BN sample 0 into h2 half 0; prefetch sample 1 ----
  uint4 pref[4];
  if (lane < 56) {
    const uint4* s0 = (const uint4*)y2h + (size_t)b0 * 224 + lane * 4;
#pragma unroll
    for (int g = 0; g < 4; ++g) pref[g] = s0[g];
#pragma unroll
    for (int g = 0; g < 4; ++g) {
      uint4 u = pref[g];
      uint4 hh;
      hh.x = pkmax0(pkfma(u.x, a2pk[g * 4 + 0], d2pk[g * 4 + 0]));
      hh.y = pkmax0(pkfma(u.y, a2pk[g * 4 + 1], d2pk[g * 4 + 1]));
      hh.z = pkmax0(pkfma(u.z, a2pk[g * 4 + 2], d2pk[g * 4 + 2]));
      hh.w = pkmax0(pkfma(u.w, a2pk[g * 4 + 3], d2pk[g * 4 + 3]));
      *(uint4*)((char*)h2b + ((lane * 64 + g * 16) ^ ((lane & 3) << 4))) = hh;
    }
    const uint4* s1 = (const uint4*)y2h + (size_t)(b0 + 1) * 224 + lane * 4;
#pragma unroll
    for (int g = 0; g < 4; ++g) pref[g] = s1[g];
  }
  int cur = 0;

  for (int r8 = 0; r8 < 8; ++r8) {
    int b = b0 + r8;
    ushort* h2 = h2b + cur * 2048;
    ushort* h2n = h2b + (cur ^ 1) * 2048;
    // ---- stage 1: QK^T = qkw @ h2^T via MFMA (4 tiles over pos) ----
    f32x4 vqk[4];
#pragma unroll
    for (int ni = 0; ni < 4; ++ni) {
      int pos = ni * 16 + lr;
      f16x8 hb2 = *(const f16x8*)((const char*)h2 + ((pos * 64 + lk * 16) ^ ((pos & 3) << 4)));
      f32x4 a = __builtin_amdgcn_mfma_f32_16x16x32_f16(qkwA, hb2, zz, 0, 0, 0);
      a[0] += biasv[0]; a[1] += biasv[1]; a[2] += biasv[2]; a[3] += biasv[3];
      vqk[ni] = a;
    }
    // ---- build score-MFMA fragments via shuffles ----
    f16x8 qfr[4], kfr[4];
#pragma unroll
    for (int t = 0; t < 4; ++t) {
      float q0 = __shfl(vqk[t][0], lr),      q1 = __shfl(vqk[t][1], lr);
      float q2 = __shfl(vqk[t][2], lr),      q3 = __shfl(vqk[t][3], lr);
      float k0 = __shfl(vqk[t][0], 16 + lr), k1 = __shfl(vqk[t][1], 16 + lr);
      float k2 = __shfl(vqk[t][2], 16 + lr), k3 = __shfl(vqk[t][3], 16 + lr);
      uint4 uq = {0u, 0u, 0u, 0u}, uk = {0u, 0u, 0u, 0u};
      if (lk == 0) {
        uq.x = pk2(q0, q1); uq.y = pk2(q2, q3);
        uk.x = pk2(k0, k1); uk.y = pk2(k2, k3);
      }
      qfr[t] = __builtin_bit_cast(f16x8, uq);
      kfr[t] = __builtin_bit_cast(f16x8, uk);
    }
    // ---- scores: S^T[j][i] via 16 MFMAs (prio-boosted) ----
    __builtin_amdgcn_s_setprio(1);
    f32x4 sac[4][4];
#pragma unroll
    for (int mi = 0; mi < 4; ++mi)
#pragma unroll
      for (int ni = 0; ni < 4; ++ni)
        sac[mi][ni] = __builtin_amdgcn_mfma_f32_16x16x32_f16(kfr[mi], qfr[ni], zz, 0, 0, 0);
    __builtin_amdgcn_s_setprio(0);
    // ---- softmax per i-row, clamp-no-max, masked j>=56; inv kept in registers ----
    float invv4[4];
#pragma unroll
    for (int ni = 0; ni < 4; ++ni) {
      float den = 0.f;
      float ev[4][4];
#pragma unroll
      for (int mi = 0; mi < 4; ++mi)
#pragma unroll
        for (int r = 0; r < 4; ++r) {
          float e = __builtin_amdgcn_exp2f(fminf(sac[mi][ni][r], 15.f));
          if (mi == 3) e = (lk < 2) ? e : 0.f;
          ev[mi][r] = e;
          den += e;
        }
      den += __shfl_xor(den, 16);
      den += __shfl_xor(den, 32);
      invv4[ni] = 1.f / den;
      int i = ni * 16 + lr;
#pragma unroll
      for (int mi = 0; mi < 4; ++mi) {
        uint2 pp;
        pp.x = pk2(ev[mi][0], ev[mi][1]);
        pp.y = pk2(ev[mi][2], ev[mi][3]);
        *(uint2*)((char*)Pl + ((i * 128 + mi * 32 + lk * 8) ^ ((lr & 7) << 4))) = pp;
      }
    }
    // ---- pipeline: BN+store NEXT sample into other h2 half (overlaps with PV below) ----
    if (r8 < 7 && lane < 56) {
#pragma unroll
      for (int g = 0; g < 4; ++g) {
        uint4 u = pref[g];
        uint4 hh;
        hh.x = pkmax0(pkfma(u.x, a2pk[g * 4 + 0], d2pk[g * 4 + 0]));
        hh.y = pkmax0(pkfma(u.y, a2pk[g * 4 + 1], d2pk[g * 4 + 1]));
        hh.z = pkmax0(pkfma(u.z, a2pk[g * 4 + 2], d2pk[g * 4 + 2]));
        hh.w = pkmax0(pkfma(u.w, a2pk[g * 4 + 3], d2pk[g * 4 + 3]));
        *(uint4*)((char*)h2n + ((lane * 64 + g * 16) ^ ((lane & 3) << 4))) = hh;
      }
      if (r8 < 6) {
        const uint4* sn = (const uint4*)y2h + (size_t)(b + 2) * 224 + lane * 4;
#pragma unroll
        for (int g = 0; g < 4; ++g) pref[g] = sn[g];
      }
    }
    // ---- gT = h2 @ vw^T : [64 j][32 c] ----
    f32x4 ga[4][2];
#pragma unroll
    for (int mi = 0; mi < 4; ++mi) {
      int rw = lr + 16 * mi;
      f16x8 af = *(const f16x8*)((const char*)h2 + ((rw * 64 + lk * 16) ^ ((rw & 3) << 4)));
#pragma unroll
      for (int ni = 0; ni < 2; ++ni)
        ga[mi][ni] = __builtin_amdgcn_mfma_f32_16x16x32_f16(af, vwf[ni], zz, 0, 0, 0);
    }
#pragma unroll
    for (int mi = 0; mi < 4; ++mi)
#pragma unroll
      for (int ni = 0; ni < 2; ++ni) {
        f32x4 v = ga[mi][ni];
        int c = lr + 16 * ni;
        int jb2 = (lk * 4 + 16 * mi) * 2;
        uint2 pp;
        pp.x = pk2(v[0], v[1]);
        pp.y = pk2(v[2], v[3]);
        *(uint2*)((char*)gl + ((c * 128 + jb2) ^ ((c & 7) << 4))) = pp;
      }
    // ---- swapped PV: out^T[c][i] = g @ P^T (prio-boosted) ----
    f32x4 oa2[2][4];
#pragma unroll
    for (int cm = 0; cm < 2; ++cm)
#pragma unroll
      for (int ni = 0; ni < 4; ++ni) oa2[cm][ni] = zz;
#pragma unroll
    for (int ks = 0; ks < 2; ++ks) {
      f16x8 gaf[2];
#pragma unroll
      for (int cm = 0; cm < 2; ++cm) {
        int c = lr + 16 * cm;
        gaf[cm] = *(const f16x8*)((const char*)gl + ((c * 128 + ks * 64 + lk * 16) ^ ((c & 7) << 4)));
      }
      f16x8 pbf[4];
#pragma unroll
      for (int ni = 0; ni < 4; ++ni) {
        int i = lr + 16 * ni;
        pbf[ni] = *(const f16x8*)((const char*)Pl + ((i * 128 + ks * 64 + lk * 16) ^ ((i & 7) << 4)));
      }
      __builtin_amdgcn_s_setprio(1);
#pragma unroll
      for (int cm = 0; cm < 2; ++cm)
#pragma unroll
        for (int ni = 0; ni < 4; ++ni)
          oa2[cm][ni] = __builtin_amdgcn_mfma_f32_16x16x32_f16(gaf[cm], pbf[ni], oa2[cm][ni], 0, 0, 0);
      __builtin_amdgcn_s_setprio(0);
    }
    // ---- epilogue: h = gamma*(vb + inv*out) + h2 -> DIRECT global store ----
    uint invpk[4];
#pragma unroll
    for (int ni = 0; ni < 4; ++ni) invpk[ni] = pk2(invv4[ni], invv4[ni]);
#pragma unroll
    for (int cm = 0; cm < 2; ++cm)
#pragma unroll
      for (int ni = 0; ni < 4; ++ni) {
        int i = lr + 16 * ni;
        uint2 h2v = *(const uint2*)((const char*)h2 + ((i * 64 + cm * 32 + lk * 8) ^ ((i & 3) << 4)));
        uint o01 = pk2(oa2[cm][ni][0], oa2[cm][ni][1]);
        uint o23 = pk2(oa2[cm][ni][2], oa2[cm][ni][3]);
        uint t0 = pkfma(o01, invpk[ni], vbpk[cm][0]);
        uint t1 = pkfma(o23, invpk[ni], vbpk[cm][1]);
        uint2 rr2;
        rr2.x = pkfma(t0, gammapk, h2v.x);
        rr2.y = pkfma(t1, gammapk, h2v.y);
        if (i < 56)
          *(uint2*)(y2h + (size_t)b * 1792 + i * 32 + cm * 16 + lk * 4) = rr2;
      }
    cur ^= 1;
  }
}

// ---------------- K4: fc1 + heads via f16 MFMA, async global->LDS staging ----------------
__global__ __launch_bounds__(256) void k_fc(
    const float* __restrict__ fc1b, const float* __restrict__ mub,
    const float* __restrict__ lvb, const float* __restrict__ ws,
    float* __restrict__ out) {
  __shared__ __align__(16) ushort At[64 * 64];
  __shared__ __align__(16) ushort Bt[256 * 64];
  __shared__ __align__(16) ushort Ft[64 * 256];
  const ushort* hbuf = (const ushort*)(ws + WS_Y2H);
  const ushort* w1bf = (const ushort*)(ws + WS_W1BF);
  const ushort* whd  = (const ushort*)(ws + WS_WHD);
  int tid = threadIdx.x, wv = tid >> 6, lane = tid & 63;
  int m0 = blockIdx.x * 64;
  int lr = lane & 15, lk = lane >> 4;
  int lrow8 = lane >> 3;                 // sub-row within a 1KB lds-load call
  int lchunk = (lane & 7) ^ lrow8;       // pre-swizzled source chunk (matches XOR read layout)

  f32x4 acc[4][4];
#pragma unroll
  for (int mi = 0; mi < 4; ++mi)
#pragma unroll
    for (int ni = 0; ni < 4; ++ni) { f32x4 z = {0.f, 0.f, 0.f, 0.f}; acc[mi][ni] = z; }

  for (int kk = 0; kk < 1792; kk += 64) {
    // stage A [64][64] via async global->LDS: 2 calls/wave, 8 rows each
#pragma unroll
    for (int j = 0; j < 2; ++j) {
      int r = wv * 16 + j * 8 + lrow8;
      gload_lds16(&hbuf[(size_t)(m0 + r) * 1792 + kk + lchunk * 8],
                  &At[(wv * 16 + j * 8) * 64]);
    }
    // stage B [256][64]: 8 calls/wave
#pragma unroll
    for (int j = 0; j < 8; ++j) {
      int r = wv * 64 + j * 8 + lrow8;
      gload_lds16(&w1bf[(size_t)r * 1792 + kk + lchunk * 8],
                  &Bt[(wv * 64 + j * 8) * 64]);
    }
    __syncthreads();
#pragma unroll
    for (int t2 = 0; t2 < 2; ++t2) {
      f16x8 af[4], bfr[4];
#pragma unroll
      for (int mi = 0; mi < 4; ++mi) {
        int rr = mi * 16 + lr;
        int ch = (t2 * 4 + lk) ^ (rr & 7);
        af[mi] = *(const f16x8*)&At[rr * 64 + ch * 8];
      }
#pragma unroll
      for (int ni = 0; ni < 4; ++ni) {
        int rr = wv * 64 + ni * 16 + lr;
        int ch = (t2 * 4 + lk) ^ (rr & 7);
        bfr[ni] = *(const f16x8*)&Bt[rr * 64 + ch * 8];
      }
#pragma unroll
      for (int mi = 0; mi < 4; ++mi)
#pragma unroll
        for (int ni = 0; ni < 4; ++ni)
          acc[mi][ni] = __builtin_amdgcn_mfma_f32_16x16x32_f16(af[mi], bfr[ni], acc[mi][ni], 0, 0, 0);
    }
    __syncthreads();
  }
#pragma unroll
  for (int ni = 0; ni < 4; ++ni) {
    int n = wv * 64 + ni * 16 + lr;
    float bj = fc1b[n];
    int lc = n >> 3;
    int nl = n & 7;
#pragma unroll
    for (int mi = 0; mi < 4; ++mi) {
      f32x4 v = acc[mi][ni];
#pragma unroll
      for (int r = 0; r < 4; ++r) {
        int m = mi * 16 + lk * 4 + r;
        int chs = (lc & ~7) | ((lc & 7) ^ (m & 7));
        Ft[m * 256 + chs * 8 + nl] = f2h(fmaxf(v[r] + bj, 0.f));
      }
    }
  }
  __syncthreads();
  f32x4 acc2[4][4];
#pragma unroll
  for (int mi = 0; mi < 4; ++mi)
#pragma unroll
    for (int ni = 0; ni < 4; ++ni) { f32x4 z = {0.f, 0.f, 0.f, 0.f}; acc2[mi][ni] = z; }
  for (int kk2 = 0; kk2 < 256; kk2 += 64) {
    // stage whd tile via async global->LDS (same swizzle mapping, stride 256)
#pragma unroll
    for (int j = 0; j < 8; ++j) {
      int r = wv * 64 + j * 8 + lrow8;
      gload_lds16(&whd[(size_t)r * 256 + kk2 + lchunk * 8],
                  &Bt[(wv * 64 + j * 8) * 64]);
    }
    __syncthreads();
#pragma unroll
    for (int t2 = 0; t2 < 2; ++t2) {
      f16x8 af[4], bfr[4];
#pragma unroll
      for (int mi = 0; mi < 4; ++mi) {
        int m = mi * 16 + lr;
        int lc = (kk2 >> 3) + t2 * 4 + lk;
        int chs = (lc & ~7) | ((lc & 7) ^ (m & 7));
        af[mi] = *(const f16x8*)&Ft[m * 256 + chs * 8];
      }
#pragma unroll
      for (int ni = 0; ni < 4; ++ni) {
        int rr = wv * 64 + ni * 16 + lr;
        int ch = (t2 * 4 + lk) ^ (rr & 7);
        bfr[ni] = *(const f16x8*)&Bt[rr * 64 + ch * 8];
      }
#pragma unroll
      for (int mi = 0; mi < 4; ++mi)
#pragma unroll
        for (int ni = 0; ni < 4; ++ni)
          acc2[mi][ni] = __builtin_amdgcn_mfma_f32_16x16x32_f16(af[mi], bfr[ni], acc2[mi][ni], 0, 0, 0);
    }
    __syncthreads();
  }
#pragma unroll
  for (int ni = 0; ni < 4; ++ni) {
    int n2 = wv * 64 + ni * 16 + lr;
    int isLv = (n2 >= 128);
    float bias2 = isLv ? lvb[n2 - 128] : mub[n2];
    size_t obase = isLv ? ((size_t)BTOT * 128 + (n2 - 128)) : (size_t)n2;
#pragma unroll
    for (int mi = 0; mi < 4; ++mi) {
      f32x4 v = acc2[mi][ni];
#pragma unroll
      for (int r = 0; r < 4; ++r) {
        int m = m0 + mi * 16 + lk * 4 + r;
        out[obase + (size_t)m * 128] = v[r] + bias2;
      }
    }
  }
}

extern "C" void kernel_launch(void* const* d_in, const int* in_sizes, int n_in,
                              void* d_out, int out_size, void* d_ws, size_t ws_size,
                              hipStream_t stream) {
  const float* x    = (const float*)d_in[0];
  const float* c1w  = (const float*)d_in[1];
  const float* bn1w = (const float*)d_in[3];
  const float* bn1b = (const float*)d_in[4];
  const float* c2w  = (const float*)d_in[5];
  const float* bn2w = (const float*)d_in[7];
  const float* bn2b = (const float*)d_in[8];
  const float* qw   = (const float*)d_in[9];
  const float* qb   = (const float*)d_in[10];
  const float* kw   = (const float*)d_in[11];
  const float* kb   = (const float*)d_in[12];
  const float* vw   = (const float*)d_in[13];
  const float* vb   = (const float*)d_in[14];
  const float* gm   = (const float*)d_in[15];
  const float* fw   = (const float*)d_in[16];
  const float* fb   = (const float*)d_in[17];
  const float* muw  = (const float*)d_in[18];
  const float* mub  = (const float*)d_in[19];
  const float* lvw  = (const float*)d_in[20];
  const float* lvb  = (const float*)d_in[21];
  float* ws = (float*)d_ws;
  float* out = (float*)d_out;

  hipMemsetAsync(d_ws, 0, 200 * sizeof(float), stream);
  hipLaunchKernelGGL(k_prep, dim3(1536), dim3(256), 0, stream,
                     x, c1w, c2w, vw, fw, muw, lvw, ws);
  hipLaunchKernelGGL(k_finalize, dim3(1), dim3(64), 0, stream, bn1w, bn1b, ws,
                     16, WS_SUM1, WS_SSQ1, WS_A1, WS_D1);
  hipLaunchKernelGGL(k_conv, dim3(1024), dim3(256), 0, stream, x, c1w, ws);
  hipLaunchKernelGGL(k_finalize, dim3(1), dim3(64), 0, stream, bn2w, bn2b, ws,
                     32, WS_SUM2, WS_SSQ2, WS_A2, WS_D2);
  hipLaunchKernelGGL(k_attn, dim3(1024), dim3(256), 0, stream,
                     qw, qb, kw, kb, vb, gm, ws);
  hipLaunchKernelGGL(k_fc, dim3(512), dim3(256), 0, stream, fb, mub, lvb, ws, out);
}